// Round 14
// baseline (83.708 us; speedup 1.0000x reference)
//
#include <hip/hip_runtime.h>
#include <hip/hip_bf16.h>
#include <math.h>

#define DIM 64
#define NROW 6400          // BS * D_NUM * SLEN
#define SLEN 50
#define NG 128             // BS * D_NUM groups
#define NEMB 512
#define SAMPLE 100         // rows per sample (mask block width)
#define NCHUNK 100         // 6400 / 64 j-chunks
#define NQB 400            // quant blocks FIRST in attn grid (r3-measured: overlap with attn)
#define SMAX 6             // r3/r8 A/B: S=6 beats S=7
#define LOG2E 1.4426950408889634f
#define SM_SHIFT2 11.541560327111707f   // 8 * log2(e): exp(s-8) == exp2(s*log2e - SM_SHIFT2)
#define LSTR 72            // LDS row stride (ushorts): 36 dwords -> 2-way-max b128 reads

typedef unsigned short ushort_t;
typedef __attribute__((ext_vector_type(8))) short short8;
typedef __attribute__((ext_vector_type(4))) float floatx4;

__device__ __forceinline__ ushort_t f2bu(float f) {
    __hip_bfloat16 h = __float2bfloat16(f);
    ushort_t u;
    __builtin_memcpy(&u, &h, 2);
    return u;
}

__device__ __forceinline__ float fast_exp2(float x) {
#if __has_builtin(__builtin_amdgcn_exp2f)
    return __builtin_amdgcn_exp2f(x);
#else
    return exp2f(x);
#endif
}

// ---------------- proj + prep fused, one projection per block (r13 form) ----------------
// blocks 0..599  : proj — block b does projection p = b%6 for row-tile b/6
// blocks 600..601: codebook f32 transpose + f64 norms
__global__ __launch_bounds__(256)
void projprep_kernel(const float* __restrict__ x,
                     const float* __restrict__ W0, const float* __restrict__ W1,
                     const float* __restrict__ W2, const float* __restrict__ W3,
                     const float* __restrict__ W4, const float* __restrict__ W5,
                     const float* __restrict__ b0, const float* __restrict__ b1,
                     const float* __restrict__ b2, const float* __restrict__ b3,
                     const float* __restrict__ b4, const float* __restrict__ b5,
                     const float* __restrict__ cb, float* __restrict__ cbT,
                     double* __restrict__ c2,
                     ushort_t* __restrict__ qib, ushort_t* __restrict__ kib,
                     ushort_t* __restrict__ vib,
                     ushort_t* __restrict__ qcb, ushort_t* __restrict__ kcb,
                     ushort_t* __restrict__ vtb)
{
    const int tid = threadIdx.x;

    if (blockIdx.x >= 600) {
        const int c = (blockIdx.x - 600) * 256 + tid;
        const float* cr = cb + (size_t)c * DIM;
        double s = 0.0;
#pragma unroll 8
        for (int e = 0; e < DIM; ++e) {
            const float v = cr[e];
            cbT[(size_t)e * NEMB + c] = v;
            s = fma((double)v, (double)v, s);
        }
        c2[c] = s;
        return;
    }

    __shared__ __align__(16) ushort_t Xb[64 * LSTR];
    __shared__ __align__(16) ushort_t WL[64 * LSTR];

    const int wave = tid >> 6, lane = tid & 63;
    const int col = lane & 15;
    const int quad = lane >> 4;

    const int r0 = (blockIdx.x / 6) * 64;
    const int p  = blockIdx.x % 6;
    const float scale = (p == 1 || p == 4) ? LOG2E : 1.0f;

    const float* W = (p == 0) ? W0 : (p == 1) ? W1 : (p == 2) ? W2
                   : (p == 3) ? W3 : (p == 4) ? W4 : W5;
    const float* B = (p == 0) ? b0 : (p == 1) ? b1 : (p == 2) ? b2
                   : (p == 3) ? b3 : (p == 4) ? b4 : b5;

    const int kr = tid >> 2, seg = tid & 3;

    {   // stage X tile as bf16
        const float* src = x + (size_t)(r0 + kr) * DIM + seg * 16;
        ushort_t* dst = &Xb[kr * LSTR + seg * 16];
#pragma unroll
        for (int i = 0; i < 16; ++i) dst[i] = f2bu(src[i]);
    }
    {   // transpose W -> WL[n][k], bf16, k-scaled
        const float* wrow = W + (size_t)kr * DIM + seg * 16;
        float wv[16];
#pragma unroll
        for (int i = 0; i < 16; ++i) wv[i] = wrow[i];
#pragma unroll
        for (int i = 0; i < 16; ++i)
            WL[(seg * 16 + i) * LSTR + kr] = f2bu(wv[i] * scale);
    }
    __syncthreads();

    const short8 aX0 = *(const short8*)&Xb[(wave * 16 + col) * LSTR + quad * 8];
    const short8 aX1 = *(const short8*)&Xb[(wave * 16 + col) * LSTR + quad * 8 + 32];

#pragma unroll
    for (int nt = 0; nt < 4; ++nt) {
        const int n = nt * 16 + col;
        float bv = B[n];
        if (p == 1 || p == 4) bv *= LOG2E;
        floatx4 c = (floatx4){bv, bv, bv, bv};
        const ushort_t* wr = &WL[n * LSTR + quad * 8];
        const short8 w0 = *(const short8*)wr;
        const short8 w1 = *(const short8*)(wr + 32);
        c = __builtin_amdgcn_mfma_f32_16x16x32_bf16(aX0, w0, c, 0, 0, 0);
        c = __builtin_amdgcn_mfma_f32_16x16x32_bf16(aX1, w1, c, 0, 0, 0);
#pragma unroll
        for (int r = 0; r < 4; ++r) {
            const int row = r0 + wave * 16 + quad * 4 + r;
            const ushort_t ub = f2bu(c[r]);
            if (p == 0)      qib[(size_t)row * DIM + n] = ub;
            else if (p == 1) kib[(size_t)row * DIM + n] = ub;
            else if (p == 2) vib[(size_t)row * DIM + n] = ub;
            else if (p == 3) qcb[(size_t)row * DIM + n] = ub;
            else if (p == 4) kcb[(size_t)row * DIM + n] = ub;
            else             vtb[(size_t)n * NROW + row] = ub;
        }
    }
}

// ---------------- fused quant + attention ----------------
// blocks [0, NQB)         : f64 quant (round-3 form, byte-identical)
// blocks [NQB, NQB+50*S)  : cross-sample flash attention, TWO 64-row i-tiles per block —
//                           staged Q/V chunk shared by both tiles: barriers, stage-writes
//                           and global fetch per unit work all halve; Pb reused per-tile
// blocks [.., +NG)        : intra-sample attention
// LDS: 27648 B -> 5 blocks/CU; launch_bounds(256,5).
__global__ __launch_bounds__(256, 5)
void attn_quant_kernel(const ushort_t* __restrict__ qib, const ushort_t* __restrict__ kib,
                       const ushort_t* __restrict__ vib, float* __restrict__ outZ,
                       const ushort_t* __restrict__ qcb, const ushort_t* __restrict__ kcb,
                       const ushort_t* __restrict__ vtb,
                       float* __restrict__ pl, float* __restrict__ pacc,
                       float* __restrict__ outX,
                       const float* __restrict__ x, const float* __restrict__ cb,
                       const float* __restrict__ cbT, const double* __restrict__ c2,
                       float* __restrict__ outq,
                       int S, int direct)
{
    __shared__ __align__(16) ushort_t smem[3 * 64 * LSTR];   // 27648 B

    const int tid = threadIdx.x;
    const int wave = tid >> 6;
    const int lane = tid & 63;

    if ((int)blockIdx.x < NQB) {
        // ======== quant: 16 rows x 512 codes, f64 (round-3 chain, bit-identical) ========
        const int r0 = blockIdx.x * 16;

        double* xs    = (double*)smem;           // [16][64]  8192 B
        double* candd = xs + 16 * 64;            // [4][16]    512 B
        int*    candi = (int*)(candd + 64);      // [4][16]    256 B
        int*    sidx  = candi + 64;              // [16]        64 B

        for (int idx = tid; idx < 16 * DIM; idx += 256) {
            const int r = idx >> 6, e = idx & 63;
            xs[r * 64 + e] = (double)x[(size_t)(r0 + r) * DIM + e];
        }
        __syncthreads();

        const int c0 = wave * 64 + lane;
        double dot0[16], dot1[16];
#pragma unroll
        for (int r = 0; r < 16; ++r) { dot0[r] = 0.0; dot1[r] = 0.0; }

        for (int e = 0; e < DIM; ++e) {
            const double ce0 = (double)cbT[(size_t)e * NEMB + c0];
            const double ce1 = (double)cbT[(size_t)e * NEMB + c0 + 256];
#pragma unroll
            for (int r = 0; r < 16; ++r) {
                const double xe = xs[r * 64 + e];
                dot0[r] = fma(xe, ce0, dot0[r]);
                dot1[r] = fma(xe, ce1, dot1[r]);
            }
        }

        const double cc0 = c2[c0];
        const double cc1 = c2[c0 + 256];
#pragma unroll
        for (int r = 0; r < 16; ++r) {
            double bd = cc0 - 2.0 * dot0[r];
            int bi = c0;
            const double d1 = cc1 - 2.0 * dot1[r];
            if (d1 < bd) { bd = d1; bi = c0 + 256; }
            for (int off = 32; off; off >>= 1) {
                const double od = __shfl_down(bd, off, 64);
                const int oi = __shfl_down(bi, off, 64);
                if (od < bd || (od == bd && oi < bi)) { bd = od; bi = oi; }
            }
            if (lane == 0) { candd[wave * 16 + r] = bd; candi[wave * 16 + r] = bi; }
        }
        __syncthreads();
        if (tid < 16) {
            double bd = candd[tid];
            int bi = candi[tid];
#pragma unroll
            for (int w = 1; w < 4; ++w) {
                const double od = candd[w * 16 + tid];
                const int oi = candi[w * 16 + tid];
                if (od < bd || (od == bd && oi < bi)) { bd = od; bi = oi; }
            }
            sidx[tid] = bi;
        }
        __syncthreads();
        for (int idx = tid; idx < 16 * DIM; idx += 256) {
            const int r = idx >> 6, e = idx & 63;
            outq[(size_t)(r0 + r) * DIM + e] = cb[(size_t)sidx[r] * DIM + e];
        }
        return;
    }

    const int ab = blockIdx.x - NQB;
    const int col = lane & 15;
    const int quad = lane >> 4;

    short8 ones;
#pragma unroll
    for (int i = 0; i < 8; ++i) ones[i] = (short)0x3F80;   // bf16 1.0

    if (ab < 50 * S) {
        // ======== cross-sample flash attention: 2 i-tiles/block, shared staging ========
        const int bi = ab / S;
        const int split = ab % S;
        const int i0 = bi * 128 + wave * 16;     // tile it rows: i0 + it*64

        ushort_t* Qs = smem;                       // [64*LSTR]
        ushort_t* Vs = smem + 64 * LSTR;           // [64*LSTR]
        ushort_t* Pb = smem + 2 * 64 * LSTR + wave * 16 * LSTR;

        const int srow = tid >> 2;
        const int sseg = tid & 3;

        short8 aK[2][2];
#pragma unroll
        for (int it = 0; it < 2; ++it) {
            const ushort_t* kr = kcb + (size_t)(i0 + it * 64 + col) * DIM + quad * 8;
            aK[it][0] = *(const short8*)kr;
            aK[it][1] = *(const short8*)(kr + 32);
        }

        int lo[2][4];
        float l[2][4];
        floatx4 O[2][4];
#pragma unroll
        for (int it = 0; it < 2; ++it)
#pragma unroll
            for (int r = 0; r < 4; ++r) {
                lo[it][r] = ((i0 + it * 64 + quad * 4 + r) / SAMPLE) * SAMPLE;
                l[it][r] = 0.f;
                O[it][r] = (floatx4){0.f, 0.f, 0.f, 0.f};
            }

        {   // prologue: stage first chunk (coalesced)
            const int j0 = split * 64;
            const uint4* qsrc = (const uint4*)(qcb + (size_t)(j0 + srow) * DIM + sseg * 16);
            const uint4* vsrc = (const uint4*)(vtb + (size_t)srow * NROW + j0 + sseg * 16);
            const uint4 q0 = qsrc[0], q1 = qsrc[1];
            const uint4 v0 = vsrc[0], v1 = vsrc[1];
            uint4* qdst = (uint4*)&Qs[srow * LSTR + sseg * 16];
            uint4* vdst = (uint4*)&Vs[srow * LSTR + sseg * 16];
            qdst[0] = q0; qdst[1] = q1;
            vdst[0] = v0; vdst[1] = v1;
        }
        __syncthreads();

        for (int ch = split; ch < NCHUNK; ch += S) {
            const int nxt = ch + S;
            uint4 q0, q1, v0, v1;
            if (nxt < NCHUNK) {   // prefetch next chunk into regs
                const int j0n = nxt * 64;
                const uint4* qsrc = (const uint4*)(qcb + (size_t)(j0n + srow) * DIM + sseg * 16);
                const uint4* vsrc = (const uint4*)(vtb + (size_t)srow * NROW + j0n + sseg * 16);
                q0 = qsrc[0]; q1 = qsrc[1];
                v0 = vsrc[0]; v1 = vsrc[1];
            }

            const int j0 = ch * 64;

#pragma unroll
            for (int it = 0; it < 2; ++it) {
                floatx4 Sv[4];
#pragma unroll
                for (int jt = 0; jt < 4; ++jt) {
                    const short8 qb0 = *(const short8*)&Qs[(jt * 16 + col) * LSTR + quad * 8];
                    const short8 qb1 = *(const short8*)&Qs[(jt * 16 + col) * LSTR + quad * 8 + 32];
                    floatx4 c = (floatx4){0.f, 0.f, 0.f, 0.f};
                    c = __builtin_amdgcn_mfma_f32_16x16x32_bf16(aK[it][0], qb0, c, 0, 0, 0);
                    c = __builtin_amdgcn_mfma_f32_16x16x32_bf16(aK[it][1], qb1, c, 0, 0, 0);
                    Sv[jt] = c;
                }

#pragma unroll
                for (int jt = 0; jt < 4; ++jt) {
                    const int jj = j0 + jt * 16 + col;
#pragma unroll
                    for (int r = 0; r < 4; ++r) {
                        float p = fast_exp2(Sv[jt][r] - SM_SHIFT2);
                        if ((unsigned)(jj - lo[it][r]) < SAMPLE) p = 0.f;   // own-sample mask
                        Pb[(quad * 4 + r) * LSTR + jt * 16 + col] = f2bu(p);
                    }
                }

                const short8 aP0 = *(const short8*)&Pb[col * LSTR + quad * 8];
                const short8 aP1 = *(const short8*)&Pb[col * LSTR + quad * 8 + 32];

                floatx4 rsv = (floatx4){0.f, 0.f, 0.f, 0.f};
                rsv = __builtin_amdgcn_mfma_f32_16x16x32_bf16(aP0, ones, rsv, 0, 0, 0);
                rsv = __builtin_amdgcn_mfma_f32_16x16x32_bf16(aP1, ones, rsv, 0, 0, 0);
#pragma unroll
                for (int r = 0; r < 4; ++r) l[it][r] += rsv[r];

#pragma unroll
                for (int et = 0; et < 4; ++et) {
                    const short8 vb0 = *(const short8*)&Vs[(et * 16 + col) * LSTR + quad * 8];
                    const short8 vb1 = *(const short8*)&Vs[(et * 16 + col) * LSTR + quad * 8 + 32];
                    O[it][et] = __builtin_amdgcn_mfma_f32_16x16x32_bf16(aP0, vb0, O[it][et], 0, 0, 0);
                    O[it][et] = __builtin_amdgcn_mfma_f32_16x16x32_bf16(aP1, vb1, O[it][et], 0, 0, 0);
                }
            }

            if (nxt < NCHUNK) {
                __syncthreads();   // all waves done reading Qs/Vs
                uint4* qdst = (uint4*)&Qs[srow * LSTR + sseg * 16];
                uint4* vdst = (uint4*)&Vs[srow * LSTR + sseg * 16];
                qdst[0] = q0; qdst[1] = q1;
                vdst[0] = v0; vdst[1] = v1;
                __syncthreads();   // writes visible
            }
        }

        if (direct) {
#pragma unroll
            for (int it = 0; it < 2; ++it)
#pragma unroll
                for (int et = 0; et < 4; ++et)
#pragma unroll
                    for (int r = 0; r < 4; ++r)
                        outX[(size_t)(i0 + it * 64 + quad * 4 + r) * DIM + et * 16 + col] =
                            O[it][et][r] / l[it][r];
        } else {
#pragma unroll
            for (int it = 0; it < 2; ++it) {
#pragma unroll
                for (int et = 0; et < 4; ++et)
#pragma unroll
                    for (int r = 0; r < 4; ++r)
                        pacc[((size_t)split * NROW + i0 + it * 64 + quad * 4 + r) * DIM + et * 16 + col] =
                            O[it][et][r];
                if (col == 0) {
#pragma unroll
                    for (int r = 0; r < 4; ++r)
                        pl[(size_t)split * NROW + i0 + it * 64 + quad * 4 + r] = l[it][r];
                }
            }
        }
    } else {
        // ======== intra-sample attention (one group per block) ========
        const int g = ab - 50 * S;
        const size_t base = (size_t)g * SLEN * DIM;

        ushort_t* Vt = smem;                              // [e][t]  9216 B
        ushort_t* Pb = smem + 64 * LSTR + wave * 16 * LSTR;

        {
            const int r = tid >> 2, seg = tid & 3;
            if (r < SLEN) {
                const uint4* vsrc = (const uint4*)(vib + base + (size_t)r * DIM + seg * 16);
                uint4 vv[2] = {vsrc[0], vsrc[1]};
                ushort_t vtmp[16];
                __builtin_memcpy(vtmp, vv, 32);
#pragma unroll
                for (int i = 0; i < 16; ++i)
                    Vt[(seg * 16 + i) * LSTR + r] = vtmp[i];
            } else {
#pragma unroll
                for (int i = 0; i < 16; ++i)
                    Vt[(seg * 16 + i) * LSTR + r] = 0;
            }
        }
        __syncthreads();

        short8 aK0, aK1;
        {
            const ushort_t* kr = kib + base + (size_t)(wave * 16 + col) * DIM + quad * 8;
            aK0 = *(const short8*)kr;
            aK1 = *(const short8*)(kr + 32);
        }

        floatx4 Sv[4];
#pragma unroll
        for (int jt = 0; jt < 4; ++jt) {
            const ushort_t* qr = qib + base + (size_t)(jt * 16 + col) * DIM + quad * 8;
            const short8 q0 = *(const short8*)qr;
            const short8 q1 = *(const short8*)(qr + 32);
            floatx4 c = (floatx4){0.f, 0.f, 0.f, 0.f};
            c = __builtin_amdgcn_mfma_f32_16x16x32_bf16(aK0, q0, c, 0, 0, 0);
            c = __builtin_amdgcn_mfma_f32_16x16x32_bf16(aK1, q1, c, 0, 0, 0);
            Sv[jt] = c;
        }

#pragma unroll
        for (int jt = 0; jt < 4; ++jt) {
            const int t = jt * 16 + col;
#pragma unroll
            for (int r = 0; r < 4; ++r) {
                float p = fast_exp2(Sv[jt][r] - SM_SHIFT2);
                if (t >= SLEN) p = 0.f;
                Pb[(quad * 4 + r) * LSTR + jt * 16 + col] = f2bu(p);
            }
        }

        const short8 aP0 = *(const short8*)&Pb[col * LSTR + quad * 8];
        const short8 aP1 = *(const short8*)&Pb[col * LSTR + quad * 8 + 32];

        floatx4 rsv = (floatx4){0.f, 0.f, 0.f, 0.f};
        rsv = __builtin_amdgcn_mfma_f32_16x16x32_bf16(aP0, ones, rsv, 0, 0, 0);
        rsv = __builtin_amdgcn_mfma_f32_16x16x32_bf16(aP1, ones, rsv, 0, 0, 0);

#pragma unroll
        for (int et = 0; et < 4; ++et) {
            const short8 v0 = *(const short8*)&Vt[(et * 16 + col) * LSTR + quad * 8];
            const short8 v1 = *(const short8*)&Vt[(et * 16 + col) * LSTR + quad * 8 + 32];
            floatx4 o = (floatx4){0.f, 0.f, 0.f, 0.f};
            o = __builtin_amdgcn_mfma_f32_16x16x32_bf16(aP0, v0, o, 0, 0, 0);
            o = __builtin_amdgcn_mfma_f32_16x16x32_bf16(aP1, v1, o, 0, 0, 0);
#pragma unroll
            for (int r = 0; r < 4; ++r) {
                const int s = wave * 16 + quad * 4 + r;
                if (s < SLEN)
                    outZ[base + (size_t)s * DIM + et * 16 + col] = o[r] / rsv[r];
            }
        }
    }
}

// ---------------- combine split-K partials: plain sums ----------------
__global__ __launch_bounds__(256)
void cs_combine_kernel(const float* __restrict__ pl, const float* __restrict__ pacc,
                       float* __restrict__ outX, int S)
{
    const int row = blockIdx.x * 4 + (threadIdx.x >> 6);
    const int lane = threadIdx.x & 63;
    float l = 0.f, a = 0.f;
    for (int p = 0; p < S; ++p) {
        l += pl[(size_t)p * NROW + row];
        a += pacc[((size_t)p * NROW + row) * DIM + lane];
    }
    outX[(size_t)row * DIM + lane] = a / l;
}

extern "C" void kernel_launch(void* const* d_in, const int* in_sizes, int n_in,
                              void* d_out, int out_size, void* d_ws, size_t ws_size,
                              hipStream_t stream)
{
    (void)in_sizes; (void)n_in; (void)out_size;

    const float* x     = (const float*)d_in[0];
    const float* cb    = (const float*)d_in[1];
    const float* Wq_is = (const float*)d_in[2];  const float* bq_is = (const float*)d_in[3];
    const float* Wk_is = (const float*)d_in[4];  const float* bk_is = (const float*)d_in[5];
    const float* Wv_is = (const float*)d_in[6];  const float* bv_is = (const float*)d_in[7];
    const float* Wq_cs = (const float*)d_in[8];  const float* bq_cs = (const float*)d_in[9];
    const float* Wk_cs = (const float*)d_in[10]; const float* bk_cs = (const float*)d_in[11];
    const float* Wv_cs = (const float*)d_in[12]; const float* bv_cs = (const float*)d_in[13];

    float* outQ = (float*)d_out;
    float* outZ = outQ + (size_t)NROW * DIM;
    float* outX = outZ + (size_t)NROW * DIM;

    const size_t RB    = (size_t)NROW * DIM * sizeof(ushort_t);
    const size_t CBT_B = (size_t)NEMB * DIM * sizeof(float);
    const size_t C2_B  = (size_t)NEMB * sizeof(double);
    const size_t BASE  = 6 * RB + CBT_B + C2_B;
    const size_t PER_SPLIT = (size_t)NROW * DIM * sizeof(float)
                           + (size_t)NROW * sizeof(float);
    int S = 1;
    if (ws_size > BASE) {
        const size_t avail = (ws_size - BASE) / PER_SPLIT;
        S = (avail >= SMAX) ? SMAX : (avail < 1 ? 1 : (int)avail);
    }
    const int direct = (S == 1);

    ushort_t* qib = (ushort_t*)d_ws;
    ushort_t* kib = qib + (size_t)NROW * DIM;
    ushort_t* vib = kib + (size_t)NROW * DIM;
    ushort_t* qcb = vib + (size_t)NROW * DIM;
    ushort_t* kcb = qcb + (size_t)NROW * DIM;
    ushort_t* vtb = kcb + (size_t)NROW * DIM;
    float*    cbT = (float*)((char*)d_ws + 6 * RB);
    double*   c2  = (double*)((char*)d_ws + 6 * RB + CBT_B);
    float*    pacc = (float*)((char*)d_ws + BASE);
    float*    pl   = pacc + (size_t)S * NROW * DIM;

    projprep_kernel<<<602, 256, 0, stream>>>(x,
        Wq_is, Wk_is, Wv_is, Wq_cs, Wk_cs, Wv_cs,
        bq_is, bk_is, bv_is, bq_cs, bk_cs, bv_cs,
        cb, cbT, c2,
        qib, kib, vib, qcb, kcb, vtb);

    attn_quant_kernel<<<NQB + 50 * S + NG, 256, 0, stream>>>(qib, kib, vib, outZ,
                                                             qcb, kcb, vtb,
                                                             pl, pacc, outX,
                                                             x, cb, cbT, c2, outQ,
                                                             S, direct);
    if (!direct)
        cs_combine_kernel<<<NROW / 4, 256, 0, stream>>>(pl, pacc, outX, S);
}

// Round 15
// 59.931 us; speedup vs baseline: 1.3967x; 1.3967x over previous
//
#include <hip/hip_runtime.h>
#include <hip/hip_bf16.h>
#include <math.h>

#define DIM 64
#define NROW 6400          // BS * D_NUM * SLEN
#define SLEN 50
#define NG 128             // BS * D_NUM groups
#define NEMB 512
#define SAMPLE 100         // rows per sample (mask block width)
#define NCHUNK 100         // 6400 / 64 j-chunks
#define NQB 400            // quant blocks FIRST in attn grid (r3-measured: overlap with attn)
#define SMAX 6             // r3/r8 A/B: S=6 beats S=7
#define LOG2E 1.4426950408889634f
#define SM_SHIFT2 11.541560327111707f   // 8 * log2(e): exp(s-8) == exp2(s*log2e - SM_SHIFT2)
#define LSTR 72            // LDS row stride (ushorts): 36 dwords -> 2-way-max b128 reads

typedef unsigned short ushort_t;
typedef __attribute__((ext_vector_type(8))) short short8;
typedef __attribute__((ext_vector_type(4))) float floatx4;

__device__ __forceinline__ ushort_t f2bu(float f) {
    __hip_bfloat16 h = __float2bfloat16(f);
    ushort_t u;
    __builtin_memcpy(&u, &h, 2);
    return u;
}

__device__ __forceinline__ float fast_exp2(float x) {
#if __has_builtin(__builtin_amdgcn_exp2f)
    return __builtin_amdgcn_exp2f(x);
#else
    return exp2f(x);
#endif
}

// ---------------- proj + prep fused, one projection per block (r13 form) ----------------
// blocks 0..599  : proj — block b does projection p = b%6 for row-tile b/6
// blocks 600..601: codebook f32 transpose + f64 norms
__global__ __launch_bounds__(256)
void projprep_kernel(const float* __restrict__ x,
                     const float* __restrict__ W0, const float* __restrict__ W1,
                     const float* __restrict__ W2, const float* __restrict__ W3,
                     const float* __restrict__ W4, const float* __restrict__ W5,
                     const float* __restrict__ b0, const float* __restrict__ b1,
                     const float* __restrict__ b2, const float* __restrict__ b3,
                     const float* __restrict__ b4, const float* __restrict__ b5,
                     const float* __restrict__ cb, float* __restrict__ cbT,
                     double* __restrict__ c2,
                     ushort_t* __restrict__ qib, ushort_t* __restrict__ kib,
                     ushort_t* __restrict__ vib,
                     ushort_t* __restrict__ qcb, ushort_t* __restrict__ kcb,
                     ushort_t* __restrict__ vtb)
{
    const int tid = threadIdx.x;

    if (blockIdx.x >= 600) {
        const int c = (blockIdx.x - 600) * 256 + tid;
        const float* cr = cb + (size_t)c * DIM;
        double s = 0.0;
#pragma unroll 8
        for (int e = 0; e < DIM; ++e) {
            const float v = cr[e];
            cbT[(size_t)e * NEMB + c] = v;
            s = fma((double)v, (double)v, s);
        }
        c2[c] = s;
        return;
    }

    __shared__ __align__(16) ushort_t Xb[64 * LSTR];
    __shared__ __align__(16) ushort_t WL[64 * LSTR];

    const int wave = tid >> 6, lane = tid & 63;
    const int col = lane & 15;
    const int quad = lane >> 4;

    const int r0 = (blockIdx.x / 6) * 64;
    const int p  = blockIdx.x % 6;
    const float scale = (p == 1 || p == 4) ? LOG2E : 1.0f;

    const float* W = (p == 0) ? W0 : (p == 1) ? W1 : (p == 2) ? W2
                   : (p == 3) ? W3 : (p == 4) ? W4 : W5;
    const float* B = (p == 0) ? b0 : (p == 1) ? b1 : (p == 2) ? b2
                   : (p == 3) ? b3 : (p == 4) ? b4 : b5;

    const int kr = tid >> 2, seg = tid & 3;

    {   // stage X tile as bf16
        const float* src = x + (size_t)(r0 + kr) * DIM + seg * 16;
        ushort_t* dst = &Xb[kr * LSTR + seg * 16];
#pragma unroll
        for (int i = 0; i < 16; ++i) dst[i] = f2bu(src[i]);
    }
    {   // transpose W -> WL[n][k], bf16, k-scaled
        const float* wrow = W + (size_t)kr * DIM + seg * 16;
        float wv[16];
#pragma unroll
        for (int i = 0; i < 16; ++i) wv[i] = wrow[i];
#pragma unroll
        for (int i = 0; i < 16; ++i)
            WL[(seg * 16 + i) * LSTR + kr] = f2bu(wv[i] * scale);
    }
    __syncthreads();

    const short8 aX0 = *(const short8*)&Xb[(wave * 16 + col) * LSTR + quad * 8];
    const short8 aX1 = *(const short8*)&Xb[(wave * 16 + col) * LSTR + quad * 8 + 32];

#pragma unroll
    for (int nt = 0; nt < 4; ++nt) {
        const int n = nt * 16 + col;
        float bv = B[n];
        if (p == 1 || p == 4) bv *= LOG2E;
        floatx4 c = (floatx4){bv, bv, bv, bv};
        const ushort_t* wr = &WL[n * LSTR + quad * 8];
        const short8 w0 = *(const short8*)wr;
        const short8 w1 = *(const short8*)(wr + 32);
        c = __builtin_amdgcn_mfma_f32_16x16x32_bf16(aX0, w0, c, 0, 0, 0);
        c = __builtin_amdgcn_mfma_f32_16x16x32_bf16(aX1, w1, c, 0, 0, 0);
#pragma unroll
        for (int r = 0; r < 4; ++r) {
            const int row = r0 + wave * 16 + quad * 4 + r;
            const ushort_t ub = f2bu(c[r]);
            if (p == 0)      qib[(size_t)row * DIM + n] = ub;
            else if (p == 1) kib[(size_t)row * DIM + n] = ub;
            else if (p == 2) vib[(size_t)row * DIM + n] = ub;
            else if (p == 3) qcb[(size_t)row * DIM + n] = ub;
            else if (p == 4) kcb[(size_t)row * DIM + n] = ub;
            else             vtb[(size_t)n * NROW + row] = ub;
        }
    }
}

// ---------------- fused quant + attention (r13 + T5 setprio on CS compute) ----------------
// blocks [0, NQB)          : f64 quant (round-3 form, byte-identical)
// blocks [NQB, NQB+100*S)  : cross-sample flash attention, single-buffer staged;
//                            compute region wrapped in s_setprio(1)/(0) — CS latency
//                            chains win issue arbitration vs co-resident quant f64 waves
// blocks [.., +NG)         : intra-sample attention
// LDS: 27648 B -> 5 blocks/CU; launch_bounds(256,5).
__global__ __launch_bounds__(256, 5)
void attn_quant_kernel(const ushort_t* __restrict__ qib, const ushort_t* __restrict__ kib,
                       const ushort_t* __restrict__ vib, float* __restrict__ outZ,
                       const ushort_t* __restrict__ qcb, const ushort_t* __restrict__ kcb,
                       const ushort_t* __restrict__ vtb,
                       float* __restrict__ pl, float* __restrict__ pacc,
                       float* __restrict__ outX,
                       const float* __restrict__ x, const float* __restrict__ cb,
                       const float* __restrict__ cbT, const double* __restrict__ c2,
                       float* __restrict__ outq,
                       int S, int direct)
{
    __shared__ __align__(16) ushort_t smem[3 * 64 * LSTR];   // 27648 B

    const int tid = threadIdx.x;
    const int wave = tid >> 6;
    const int lane = tid & 63;

    if ((int)blockIdx.x < NQB) {
        // ======== quant: 16 rows x 512 codes, f64 (round-3 chain, bit-identical) ========
        const int r0 = blockIdx.x * 16;

        double* xs    = (double*)smem;           // [16][64]  8192 B
        double* candd = xs + 16 * 64;            // [4][16]    512 B
        int*    candi = (int*)(candd + 64);      // [4][16]    256 B
        int*    sidx  = candi + 64;              // [16]        64 B

        for (int idx = tid; idx < 16 * DIM; idx += 256) {
            const int r = idx >> 6, e = idx & 63;
            xs[r * 64 + e] = (double)x[(size_t)(r0 + r) * DIM + e];
        }
        __syncthreads();

        const int c0 = wave * 64 + lane;
        double dot0[16], dot1[16];
#pragma unroll
        for (int r = 0; r < 16; ++r) { dot0[r] = 0.0; dot1[r] = 0.0; }

        for (int e = 0; e < DIM; ++e) {
            const double ce0 = (double)cbT[(size_t)e * NEMB + c0];
            const double ce1 = (double)cbT[(size_t)e * NEMB + c0 + 256];
#pragma unroll
            for (int r = 0; r < 16; ++r) {
                const double xe = xs[r * 64 + e];
                dot0[r] = fma(xe, ce0, dot0[r]);
                dot1[r] = fma(xe, ce1, dot1[r]);
            }
        }

        const double cc0 = c2[c0];
        const double cc1 = c2[c0 + 256];
#pragma unroll
        for (int r = 0; r < 16; ++r) {
            double bd = cc0 - 2.0 * dot0[r];
            int bi = c0;
            const double d1 = cc1 - 2.0 * dot1[r];
            if (d1 < bd) { bd = d1; bi = c0 + 256; }
            for (int off = 32; off; off >>= 1) {
                const double od = __shfl_down(bd, off, 64);
                const int oi = __shfl_down(bi, off, 64);
                if (od < bd || (od == bd && oi < bi)) { bd = od; bi = oi; }
            }
            if (lane == 0) { candd[wave * 16 + r] = bd; candi[wave * 16 + r] = bi; }
        }
        __syncthreads();
        if (tid < 16) {
            double bd = candd[tid];
            int bi = candi[tid];
#pragma unroll
            for (int w = 1; w < 4; ++w) {
                const double od = candd[w * 16 + tid];
                const int oi = candi[w * 16 + tid];
                if (od < bd || (od == bd && oi < bi)) { bd = od; bi = oi; }
            }
            sidx[tid] = bi;
        }
        __syncthreads();
        for (int idx = tid; idx < 16 * DIM; idx += 256) {
            const int r = idx >> 6, e = idx & 63;
            outq[(size_t)(r0 + r) * DIM + e] = cb[(size_t)sidx[r] * DIM + e];
        }
        return;
    }

    const int ab = blockIdx.x - NQB;
    const int col = lane & 15;
    const int quad = lane >> 4;

    short8 ones;
#pragma unroll
    for (int i = 0; i < 8; ++i) ones[i] = (short)0x3F80;   // bf16 1.0

    if (ab < 100 * S) {
        // ======== cross-sample flash attention: single-buffer staged, reg prefetch ========
        const int bi = ab / S;
        const int split = ab % S;
        const int i0 = bi * 64 + wave * 16;

        ushort_t* Qs = smem;                       // [64*LSTR]
        ushort_t* Vs = smem + 64 * LSTR;           // [64*LSTR]
        ushort_t* Pb = smem + 2 * 64 * LSTR + wave * 16 * LSTR;

        const int srow = tid >> 2;
        const int sseg = tid & 3;

        short8 aK0, aK1;
        {
            const ushort_t* kr = kcb + (size_t)(i0 + col) * DIM + quad * 8;
            aK0 = *(const short8*)kr;
            aK1 = *(const short8*)(kr + 32);
        }

        int lo[4];
        float l[4];
        floatx4 O[4];
#pragma unroll
        for (int r = 0; r < 4; ++r) {
            lo[r] = ((i0 + quad * 4 + r) / SAMPLE) * SAMPLE;
            l[r] = 0.f;
        }
#pragma unroll
        for (int et = 0; et < 4; ++et) O[et] = (floatx4){0.f, 0.f, 0.f, 0.f};

        {   // prologue: stage first chunk (coalesced)
            const int j0 = split * 64;
            const uint4* qsrc = (const uint4*)(qcb + (size_t)(j0 + srow) * DIM + sseg * 16);
            const uint4* vsrc = (const uint4*)(vtb + (size_t)srow * NROW + j0 + sseg * 16);
            const uint4 q0 = qsrc[0], q1 = qsrc[1];
            const uint4 v0 = vsrc[0], v1 = vsrc[1];
            uint4* qdst = (uint4*)&Qs[srow * LSTR + sseg * 16];
            uint4* vdst = (uint4*)&Vs[srow * LSTR + sseg * 16];
            qdst[0] = q0; qdst[1] = q1;
            vdst[0] = v0; vdst[1] = v1;
        }
        __syncthreads();

        for (int ch = split; ch < NCHUNK; ch += S) {
            const int nxt = ch + S;
            uint4 q0, q1, v0, v1;
            if (nxt < NCHUNK) {   // prefetch next chunk into regs
                const int j0n = nxt * 64;
                const uint4* qsrc = (const uint4*)(qcb + (size_t)(j0n + srow) * DIM + sseg * 16);
                const uint4* vsrc = (const uint4*)(vtb + (size_t)srow * NROW + j0n + sseg * 16);
                q0 = qsrc[0]; q1 = qsrc[1];
                v0 = vsrc[0]; v1 = vsrc[1];
            }

            const int j0 = ch * 64;

            __builtin_amdgcn_s_setprio(1);   // T5: CS compute wins arbitration vs quant waves

            floatx4 Sv[4];
#pragma unroll
            for (int jt = 0; jt < 4; ++jt) {
                const short8 b0 = *(const short8*)&Qs[(jt * 16 + col) * LSTR + quad * 8];
                const short8 b1 = *(const short8*)&Qs[(jt * 16 + col) * LSTR + quad * 8 + 32];
                floatx4 c = (floatx4){0.f, 0.f, 0.f, 0.f};
                c = __builtin_amdgcn_mfma_f32_16x16x32_bf16(aK0, b0, c, 0, 0, 0);
                c = __builtin_amdgcn_mfma_f32_16x16x32_bf16(aK1, b1, c, 0, 0, 0);
                Sv[jt] = c;
            }

#pragma unroll
            for (int jt = 0; jt < 4; ++jt) {
                const int jj = j0 + jt * 16 + col;
#pragma unroll
                for (int r = 0; r < 4; ++r) {
                    float p = fast_exp2(Sv[jt][r] - SM_SHIFT2);
                    if ((unsigned)(jj - lo[r]) < SAMPLE) p = 0.f;   // own-sample mask
                    Pb[(quad * 4 + r) * LSTR + jt * 16 + col] = f2bu(p);
                }
            }

            const short8 aP0 = *(const short8*)&Pb[col * LSTR + quad * 8];
            const short8 aP1 = *(const short8*)&Pb[col * LSTR + quad * 8 + 32];

            floatx4 rsv = (floatx4){0.f, 0.f, 0.f, 0.f};
            rsv = __builtin_amdgcn_mfma_f32_16x16x32_bf16(aP0, ones, rsv, 0, 0, 0);
            rsv = __builtin_amdgcn_mfma_f32_16x16x32_bf16(aP1, ones, rsv, 0, 0, 0);
#pragma unroll
            for (int r = 0; r < 4; ++r) l[r] += rsv[r];

#pragma unroll
            for (int et = 0; et < 4; ++et) {
                const short8 b0 = *(const short8*)&Vs[(et * 16 + col) * LSTR + quad * 8];
                const short8 b1 = *(const short8*)&Vs[(et * 16 + col) * LSTR + quad * 8 + 32];
                O[et] = __builtin_amdgcn_mfma_f32_16x16x32_bf16(aP0, b0, O[et], 0, 0, 0);
                O[et] = __builtin_amdgcn_mfma_f32_16x16x32_bf16(aP1, b1, O[et], 0, 0, 0);
            }

            __builtin_amdgcn_s_setprio(0);

            if (nxt < NCHUNK) {
                __syncthreads();   // all waves done reading Qs/Vs
                uint4* qdst = (uint4*)&Qs[srow * LSTR + sseg * 16];
                uint4* vdst = (uint4*)&Vs[srow * LSTR + sseg * 16];
                qdst[0] = q0; qdst[1] = q1;
                vdst[0] = v0; vdst[1] = v1;
                __syncthreads();   // writes visible
            }
        }

        if (direct) {
#pragma unroll
            for (int et = 0; et < 4; ++et)
#pragma unroll
                for (int r = 0; r < 4; ++r)
                    outX[(size_t)(i0 + quad * 4 + r) * DIM + et * 16 + col] = O[et][r] / l[r];
        } else {
#pragma unroll
            for (int et = 0; et < 4; ++et)
#pragma unroll
                for (int r = 0; r < 4; ++r)
                    pacc[((size_t)split * NROW + i0 + quad * 4 + r) * DIM + et * 16 + col] = O[et][r];
            if (col == 0) {
#pragma unroll
                for (int r = 0; r < 4; ++r)
                    pl[(size_t)split * NROW + i0 + quad * 4 + r] = l[r];
            }
        }
    } else {
        // ======== intra-sample attention (one group per block) ========
        const int g = ab - 100 * S;
        const size_t base = (size_t)g * SLEN * DIM;

        ushort_t* Vt = smem;                              // [e][t]  9216 B
        ushort_t* Pb = smem + 64 * LSTR + wave * 16 * LSTR;

        {
            const int r = tid >> 2, seg = tid & 3;
            if (r < SLEN) {
                const uint4* vsrc = (const uint4*)(vib + base + (size_t)r * DIM + seg * 16);
                uint4 vv[2] = {vsrc[0], vsrc[1]};
                ushort_t vtmp[16];
                __builtin_memcpy(vtmp, vv, 32);
#pragma unroll
                for (int i = 0; i < 16; ++i)
                    Vt[(seg * 16 + i) * LSTR + r] = vtmp[i];
            } else {
#pragma unroll
                for (int i = 0; i < 16; ++i)
                    Vt[(seg * 16 + i) * LSTR + r] = 0;
            }
        }
        __syncthreads();

        short8 aK0, aK1;
        {
            const ushort_t* kr = kib + base + (size_t)(wave * 16 + col) * DIM + quad * 8;
            aK0 = *(const short8*)kr;
            aK1 = *(const short8*)(kr + 32);
        }

        floatx4 Sv[4];
#pragma unroll
        for (int jt = 0; jt < 4; ++jt) {
            const ushort_t* qr = qib + base + (size_t)(jt * 16 + col) * DIM + quad * 8;
            const short8 q0 = *(const short8*)qr;
            const short8 q1 = *(const short8*)(qr + 32);
            floatx4 c = (floatx4){0.f, 0.f, 0.f, 0.f};
            c = __builtin_amdgcn_mfma_f32_16x16x32_bf16(aK0, q0, c, 0, 0, 0);
            c = __builtin_amdgcn_mfma_f32_16x16x32_bf16(aK1, q1, c, 0, 0, 0);
            Sv[jt] = c;
        }

#pragma unroll
        for (int jt = 0; jt < 4; ++jt) {
            const int t = jt * 16 + col;
#pragma unroll
            for (int r = 0; r < 4; ++r) {
                float p = fast_exp2(Sv[jt][r] - SM_SHIFT2);
                if (t >= SLEN) p = 0.f;
                Pb[(quad * 4 + r) * LSTR + jt * 16 + col] = f2bu(p);
            }
        }

        const short8 aP0 = *(const short8*)&Pb[col * LSTR + quad * 8];
        const short8 aP1 = *(const short8*)&Pb[col * LSTR + quad * 8 + 32];

        floatx4 rsv = (floatx4){0.f, 0.f, 0.f, 0.f};
        rsv = __builtin_amdgcn_mfma_f32_16x16x32_bf16(aP0, ones, rsv, 0, 0, 0);
        rsv = __builtin_amdgcn_mfma_f32_16x16x32_bf16(aP1, ones, rsv, 0, 0, 0);

#pragma unroll
        for (int et = 0; et < 4; ++et) {
            const short8 v0 = *(const short8*)&Vt[(et * 16 + col) * LSTR + quad * 8];
            const short8 v1 = *(const short8*)&Vt[(et * 16 + col) * LSTR + quad * 8 + 32];
            floatx4 o = (floatx4){0.f, 0.f, 0.f, 0.f};
            o = __builtin_amdgcn_mfma_f32_16x16x32_bf16(aP0, v0, o, 0, 0, 0);
            o = __builtin_amdgcn_mfma_f32_16x16x32_bf16(aP1, v1, o, 0, 0, 0);
#pragma unroll
            for (int r = 0; r < 4; ++r) {
                const int s = wave * 16 + quad * 4 + r;
                if (s < SLEN)
                    outZ[base + (size_t)s * DIM + et * 16 + col] = o[r] / rsv[r];
            }
        }
    }
}

// ---------------- combine split-K partials: plain sums ----------------
__global__ __launch_bounds__(256)
void cs_combine_kernel(const float* __restrict__ pl, const float* __restrict__ pacc,
                       float* __restrict__ outX, int S)
{
    const int row = blockIdx.x * 4 + (threadIdx.x >> 6);
    const int lane = threadIdx.x & 63;
    float l = 0.f, a = 0.f;
    for (int p = 0; p < S; ++p) {
        l += pl[(size_t)p * NROW + row];
        a += pacc[((size_t)p * NROW + row) * DIM + lane];
    }
    outX[(size_t)row * DIM + lane] = a / l;
}

extern "C" void kernel_launch(void* const* d_in, const int* in_sizes, int n_in,
                              void* d_out, int out_size, void* d_ws, size_t ws_size,
                              hipStream_t stream)
{
    (void)in_sizes; (void)n_in; (void)out_size;

    const float* x     = (const float*)d_in[0];
    const float* cb    = (const float*)d_in[1];
    const float* Wq_is = (const float*)d_in[2];  const float* bq_is = (const float*)d_in[3];
    const float* Wk_is = (const float*)d_in[4];  const float* bk_is = (const float*)d_in[5];
    const float* Wv_is = (const float*)d_in[6];  const float* bv_is = (const float*)d_in[7];
    const float* Wq_cs = (const float*)d_in[8];  const float* bq_cs = (const float*)d_in[9];
    const float* Wk_cs = (const float*)d_in[10]; const float* bk_cs = (const float*)d_in[11];
    const float* Wv_cs = (const float*)d_in[12]; const float* bv_cs = (const float*)d_in[13];

    float* outQ = (float*)d_out;
    float* outZ = outQ + (size_t)NROW * DIM;
    float* outX = outZ + (size_t)NROW * DIM;

    const size_t RB    = (size_t)NROW * DIM * sizeof(ushort_t);
    const size_t CBT_B = (size_t)NEMB * DIM * sizeof(float);
    const size_t C2_B  = (size_t)NEMB * sizeof(double);
    const size_t BASE  = 6 * RB + CBT_B + C2_B;
    const size_t PER_SPLIT = (size_t)NROW * DIM * sizeof(float)
                           + (size_t)NROW * sizeof(float);
    int S = 1;
    if (ws_size > BASE) {
        const size_t avail = (ws_size - BASE) / PER_SPLIT;
        S = (avail >= SMAX) ? SMAX : (avail < 1 ? 1 : (int)avail);
    }
    const int direct = (S == 1);

    ushort_t* qib = (ushort_t*)d_ws;
    ushort_t* kib = qib + (size_t)NROW * DIM;
    ushort_t* vib = kib + (size_t)NROW * DIM;
    ushort_t* qcb = vib + (size_t)NROW * DIM;
    ushort_t* kcb = qcb + (size_t)NROW * DIM;
    ushort_t* vtb = kcb + (size_t)NROW * DIM;
    float*    cbT = (float*)((char*)d_ws + 6 * RB);
    double*   c2  = (double*)((char*)d_ws + 6 * RB + CBT_B);
    float*    pacc = (float*)((char*)d_ws + BASE);
    float*    pl   = pacc + (size_t)S * NROW * DIM;

    projprep_kernel<<<602, 256, 0, stream>>>(x,
        Wq_is, Wk_is, Wv_is, Wq_cs, Wk_cs, Wv_cs,
        bq_is, bk_is, bv_is, bq_cs, bk_cs, bv_cs,
        cb, cbT, c2,
        qib, kib, vib, qcb, kcb, vtb);

    attn_quant_kernel<<<NQB + 100 * S + NG, 256, 0, stream>>>(qib, kib, vib, outZ,
                                                              qcb, kcb, vtb,
                                                              pl, pacc, outX,
                                                              x, cb, cbT, c2, outQ,
                                                              S, direct);
    if (!direct)
        cs_combine_kernel<<<NROW / 4, 256, 0, stream>>>(pl, pacc, outX, S);
}

// Round 16
// 55.453 us; speedup vs baseline: 1.5095x; 1.0808x over previous
//
#include <hip/hip_runtime.h>
#include <hip/hip_bf16.h>
#include <math.h>

#define DIM 64
#define NROW 6400          // BS * D_NUM * SLEN
#define SLEN 50
#define NG 128             // BS * D_NUM groups
#define NEMB 512
#define SAMPLE 100         // rows per sample (mask block width)
#define NCHUNK 100         // 6400 / 64 j-chunks
#define NQB 400            // quant blocks FIRST in attn grid (r3-measured: overlap with attn)
#define SMAX 6             // r3/r8 A/B: S=6 beats S=7
#define LOG2E 1.4426950408889634f
#define SM_SHIFT2 11.541560327111707f   // 8 * log2(e): exp(s-8) == exp2(s*log2e - SM_SHIFT2)
#define LSTR 72            // LDS row stride (ushorts): 36 dwords -> 2-way-max b128 reads

typedef unsigned short ushort_t;
typedef __attribute__((ext_vector_type(8))) short short8;
typedef __attribute__((ext_vector_type(4))) float floatx4;

__device__ __forceinline__ ushort_t f2bu(float f) {
    __hip_bfloat16 h = __float2bfloat16(f);
    ushort_t u;
    __builtin_memcpy(&u, &h, 2);
    return u;
}

__device__ __forceinline__ float fast_exp2(float x) {
#if __has_builtin(__builtin_amdgcn_exp2f)
    return __builtin_amdgcn_exp2f(x);
#else
    return exp2f(x);
#endif
}

// ---------------- proj + prep fused, one projection per block (r13 form) ----------------
// blocks 0..599  : proj — block b does projection p = b%6 for row-tile b/6
// blocks 600..601: codebook f32 transpose + f64 norms
__global__ __launch_bounds__(256)
void projprep_kernel(const float* __restrict__ x,
                     const float* __restrict__ W0, const float* __restrict__ W1,
                     const float* __restrict__ W2, const float* __restrict__ W3,
                     const float* __restrict__ W4, const float* __restrict__ W5,
                     const float* __restrict__ b0, const float* __restrict__ b1,
                     const float* __restrict__ b2, const float* __restrict__ b3,
                     const float* __restrict__ b4, const float* __restrict__ b5,
                     const float* __restrict__ cb, float* __restrict__ cbT,
                     double* __restrict__ c2,
                     ushort_t* __restrict__ qib, ushort_t* __restrict__ kib,
                     ushort_t* __restrict__ vib,
                     ushort_t* __restrict__ qcb, ushort_t* __restrict__ kcb,
                     ushort_t* __restrict__ vtb)
{
    const int tid = threadIdx.x;

    if (blockIdx.x >= 600) {
        const int c = (blockIdx.x - 600) * 256 + tid;
        const float* cr = cb + (size_t)c * DIM;
        double s = 0.0;
#pragma unroll 8
        for (int e = 0; e < DIM; ++e) {
            const float v = cr[e];
            cbT[(size_t)e * NEMB + c] = v;
            s = fma((double)v, (double)v, s);
        }
        c2[c] = s;
        return;
    }

    __shared__ __align__(16) ushort_t Xb[64 * LSTR];
    __shared__ __align__(16) ushort_t WL[64 * LSTR];

    const int wave = tid >> 6, lane = tid & 63;
    const int col = lane & 15;
    const int quad = lane >> 4;

    const int r0 = (blockIdx.x / 6) * 64;
    const int p  = blockIdx.x % 6;
    const float scale = (p == 1 || p == 4) ? LOG2E : 1.0f;

    const float* W = (p == 0) ? W0 : (p == 1) ? W1 : (p == 2) ? W2
                   : (p == 3) ? W3 : (p == 4) ? W4 : W5;
    const float* B = (p == 0) ? b0 : (p == 1) ? b1 : (p == 2) ? b2
                   : (p == 3) ? b3 : (p == 4) ? b4 : b5;

    const int kr = tid >> 2, seg = tid & 3;

    {   // stage X tile as bf16
        const float* src = x + (size_t)(r0 + kr) * DIM + seg * 16;
        ushort_t* dst = &Xb[kr * LSTR + seg * 16];
#pragma unroll
        for (int i = 0; i < 16; ++i) dst[i] = f2bu(src[i]);
    }
    {   // transpose W -> WL[n][k], bf16, k-scaled
        const float* wrow = W + (size_t)kr * DIM + seg * 16;
        float wv[16];
#pragma unroll
        for (int i = 0; i < 16; ++i) wv[i] = wrow[i];
#pragma unroll
        for (int i = 0; i < 16; ++i)
            WL[(seg * 16 + i) * LSTR + kr] = f2bu(wv[i] * scale);
    }
    __syncthreads();

    const short8 aX0 = *(const short8*)&Xb[(wave * 16 + col) * LSTR + quad * 8];
    const short8 aX1 = *(const short8*)&Xb[(wave * 16 + col) * LSTR + quad * 8 + 32];

#pragma unroll
    for (int nt = 0; nt < 4; ++nt) {
        const int n = nt * 16 + col;
        float bv = B[n];
        if (p == 1 || p == 4) bv *= LOG2E;
        floatx4 c = (floatx4){bv, bv, bv, bv};
        const ushort_t* wr = &WL[n * LSTR + quad * 8];
        const short8 w0 = *(const short8*)wr;
        const short8 w1 = *(const short8*)(wr + 32);
        c = __builtin_amdgcn_mfma_f32_16x16x32_bf16(aX0, w0, c, 0, 0, 0);
        c = __builtin_amdgcn_mfma_f32_16x16x32_bf16(aX1, w1, c, 0, 0, 0);
#pragma unroll
        for (int r = 0; r < 4; ++r) {
            const int row = r0 + wave * 16 + quad * 4 + r;
            const ushort_t ub = f2bu(c[r]);
            if (p == 0)      qib[(size_t)row * DIM + n] = ub;
            else if (p == 1) kib[(size_t)row * DIM + n] = ub;
            else if (p == 2) vib[(size_t)row * DIM + n] = ub;
            else if (p == 3) qcb[(size_t)row * DIM + n] = ub;
            else if (p == 4) kcb[(size_t)row * DIM + n] = ub;
            else             vtb[(size_t)n * NROW + row] = ub;
        }
    }
}

// ---------------- fused quant + attention (round-13 verified form, S=6) ----------------
// blocks [0, NQB)          : f64 quant (LDS xs, f32 cbT, f64 chain)
// blocks [NQB, NQB+100*S)  : cross-sample flash attention, single-buffer staged
// blocks [.., +NG)         : intra-sample attention
// LDS: 27648 B -> 5 blocks/CU; launch_bounds(256,5).
__global__ __launch_bounds__(256, 5)
void attn_quant_kernel(const ushort_t* __restrict__ qib, const ushort_t* __restrict__ kib,
                       const ushort_t* __restrict__ vib, float* __restrict__ outZ,
                       const ushort_t* __restrict__ qcb, const ushort_t* __restrict__ kcb,
                       const ushort_t* __restrict__ vtb,
                       float* __restrict__ pl, float* __restrict__ pacc,
                       float* __restrict__ outX,
                       const float* __restrict__ x, const float* __restrict__ cb,
                       const float* __restrict__ cbT, const double* __restrict__ c2,
                       float* __restrict__ outq,
                       int S, int direct)
{
    __shared__ __align__(16) ushort_t smem[3 * 64 * LSTR];   // 27648 B

    const int tid = threadIdx.x;
    const int wave = tid >> 6;
    const int lane = tid & 63;

    if ((int)blockIdx.x < NQB) {
        // ======== quant: 16 rows x 512 codes, f64 (round-3 chain, bit-identical) ========
        // argmin_n ( c2[n] - 2*dot(x[m],cb[n]) )   (||x||^2 per-row const: argmin-invariant)
        const int r0 = blockIdx.x * 16;

        double* xs    = (double*)smem;           // [16][64]  8192 B
        double* candd = xs + 16 * 64;            // [4][16]    512 B
        int*    candi = (int*)(candd + 64);      // [4][16]    256 B
        int*    sidx  = candi + 64;              // [16]        64 B

        for (int idx = tid; idx < 16 * DIM; idx += 256) {
            const int r = idx >> 6, e = idx & 63;
            xs[r * 64 + e] = (double)x[(size_t)(r0 + r) * DIM + e];
        }
        __syncthreads();

        const int c0 = wave * 64 + lane;
        double dot0[16], dot1[16];
#pragma unroll
        for (int r = 0; r < 16; ++r) { dot0[r] = 0.0; dot1[r] = 0.0; }

        for (int e = 0; e < DIM; ++e) {
            const double ce0 = (double)cbT[(size_t)e * NEMB + c0];
            const double ce1 = (double)cbT[(size_t)e * NEMB + c0 + 256];
#pragma unroll
            for (int r = 0; r < 16; ++r) {
                const double xe = xs[r * 64 + e];
                dot0[r] = fma(xe, ce0, dot0[r]);
                dot1[r] = fma(xe, ce1, dot1[r]);
            }
        }

        const double cc0 = c2[c0];
        const double cc1 = c2[c0 + 256];
#pragma unroll
        for (int r = 0; r < 16; ++r) {
            double bd = cc0 - 2.0 * dot0[r];
            int bi = c0;
            const double d1 = cc1 - 2.0 * dot1[r];
            if (d1 < bd) { bd = d1; bi = c0 + 256; }
            for (int off = 32; off; off >>= 1) {
                const double od = __shfl_down(bd, off, 64);
                const int oi = __shfl_down(bi, off, 64);
                if (od < bd || (od == bd && oi < bi)) { bd = od; bi = oi; }
            }
            if (lane == 0) { candd[wave * 16 + r] = bd; candi[wave * 16 + r] = bi; }
        }
        __syncthreads();
        if (tid < 16) {
            double bd = candd[tid];
            int bi = candi[tid];
#pragma unroll
            for (int w = 1; w < 4; ++w) {
                const double od = candd[w * 16 + tid];
                const int oi = candi[w * 16 + tid];
                if (od < bd || (od == bd && oi < bi)) { bd = od; bi = oi; }
            }
            sidx[tid] = bi;
        }
        __syncthreads();
        for (int idx = tid; idx < 16 * DIM; idx += 256) {
            const int r = idx >> 6, e = idx & 63;
            outq[(size_t)(r0 + r) * DIM + e] = cb[(size_t)sidx[r] * DIM + e];
        }
        return;
    }

    const int ab = blockIdx.x - NQB;
    const int col = lane & 15;
    const int quad = lane >> 4;

    short8 ones;
#pragma unroll
    for (int i = 0; i < 8; ++i) ones[i] = (short)0x3F80;   // bf16 1.0

    if (ab < 100 * S) {
        // ======== cross-sample flash attention: single-buffer staged, reg prefetch ========
        const int bi = ab / S;
        const int split = ab % S;
        const int i0 = bi * 64 + wave * 16;

        ushort_t* Qs = smem;                       // [64*LSTR]
        ushort_t* Vs = smem + 64 * LSTR;           // [64*LSTR]
        ushort_t* Pb = smem + 2 * 64 * LSTR + wave * 16 * LSTR;

        const int srow = tid >> 2;
        const int sseg = tid & 3;

        short8 aK0, aK1;
        {
            const ushort_t* kr = kcb + (size_t)(i0 + col) * DIM + quad * 8;
            aK0 = *(const short8*)kr;
            aK1 = *(const short8*)(kr + 32);
        }

        int lo[4];
        float l[4];
        floatx4 O[4];
#pragma unroll
        for (int r = 0; r < 4; ++r) {
            lo[r] = ((i0 + quad * 4 + r) / SAMPLE) * SAMPLE;
            l[r] = 0.f;
        }
#pragma unroll
        for (int et = 0; et < 4; ++et) O[et] = (floatx4){0.f, 0.f, 0.f, 0.f};

        {   // prologue: stage first chunk (coalesced)
            const int j0 = split * 64;
            const uint4* qsrc = (const uint4*)(qcb + (size_t)(j0 + srow) * DIM + sseg * 16);
            const uint4* vsrc = (const uint4*)(vtb + (size_t)srow * NROW + j0 + sseg * 16);
            const uint4 q0 = qsrc[0], q1 = qsrc[1];
            const uint4 v0 = vsrc[0], v1 = vsrc[1];
            uint4* qdst = (uint4*)&Qs[srow * LSTR + sseg * 16];
            uint4* vdst = (uint4*)&Vs[srow * LSTR + sseg * 16];
            qdst[0] = q0; qdst[1] = q1;
            vdst[0] = v0; vdst[1] = v1;
        }
        __syncthreads();

        for (int ch = split; ch < NCHUNK; ch += S) {
            const int nxt = ch + S;
            uint4 q0, q1, v0, v1;
            if (nxt < NCHUNK) {   // prefetch next chunk into regs
                const int j0n = nxt * 64;
                const uint4* qsrc = (const uint4*)(qcb + (size_t)(j0n + srow) * DIM + sseg * 16);
                const uint4* vsrc = (const uint4*)(vtb + (size_t)srow * NROW + j0n + sseg * 16);
                q0 = qsrc[0]; q1 = qsrc[1];
                v0 = vsrc[0]; v1 = vsrc[1];
            }

            const int j0 = ch * 64;

            floatx4 Sv[4];
#pragma unroll
            for (int jt = 0; jt < 4; ++jt) {
                const short8 b0 = *(const short8*)&Qs[(jt * 16 + col) * LSTR + quad * 8];
                const short8 b1 = *(const short8*)&Qs[(jt * 16 + col) * LSTR + quad * 8 + 32];
                floatx4 c = (floatx4){0.f, 0.f, 0.f, 0.f};
                c = __builtin_amdgcn_mfma_f32_16x16x32_bf16(aK0, b0, c, 0, 0, 0);
                c = __builtin_amdgcn_mfma_f32_16x16x32_bf16(aK1, b1, c, 0, 0, 0);
                Sv[jt] = c;
            }

#pragma unroll
            for (int jt = 0; jt < 4; ++jt) {
                const int jj = j0 + jt * 16 + col;
#pragma unroll
                for (int r = 0; r < 4; ++r) {
                    float p = fast_exp2(Sv[jt][r] - SM_SHIFT2);
                    if ((unsigned)(jj - lo[r]) < SAMPLE) p = 0.f;   // own-sample mask
                    Pb[(quad * 4 + r) * LSTR + jt * 16 + col] = f2bu(p);
                }
            }

            const short8 aP0 = *(const short8*)&Pb[col * LSTR + quad * 8];
            const short8 aP1 = *(const short8*)&Pb[col * LSTR + quad * 8 + 32];

            floatx4 rsv = (floatx4){0.f, 0.f, 0.f, 0.f};
            rsv = __builtin_amdgcn_mfma_f32_16x16x32_bf16(aP0, ones, rsv, 0, 0, 0);
            rsv = __builtin_amdgcn_mfma_f32_16x16x32_bf16(aP1, ones, rsv, 0, 0, 0);
#pragma unroll
            for (int r = 0; r < 4; ++r) l[r] += rsv[r];

#pragma unroll
            for (int et = 0; et < 4; ++et) {
                const short8 b0 = *(const short8*)&Vs[(et * 16 + col) * LSTR + quad * 8];
                const short8 b1 = *(const short8*)&Vs[(et * 16 + col) * LSTR + quad * 8 + 32];
                O[et] = __builtin_amdgcn_mfma_f32_16x16x32_bf16(aP0, b0, O[et], 0, 0, 0);
                O[et] = __builtin_amdgcn_mfma_f32_16x16x32_bf16(aP1, b1, O[et], 0, 0, 0);
            }

            if (nxt < NCHUNK) {
                __syncthreads();   // all waves done reading Qs/Vs
                uint4* qdst = (uint4*)&Qs[srow * LSTR + sseg * 16];
                uint4* vdst = (uint4*)&Vs[srow * LSTR + sseg * 16];
                qdst[0] = q0; qdst[1] = q1;
                vdst[0] = v0; vdst[1] = v1;
                __syncthreads();   // writes visible
            }
        }

        if (direct) {
#pragma unroll
            for (int et = 0; et < 4; ++et)
#pragma unroll
                for (int r = 0; r < 4; ++r)
                    outX[(size_t)(i0 + quad * 4 + r) * DIM + et * 16 + col] = O[et][r] / l[r];
        } else {
#pragma unroll
            for (int et = 0; et < 4; ++et)
#pragma unroll
                for (int r = 0; r < 4; ++r)
                    pacc[((size_t)split * NROW + i0 + quad * 4 + r) * DIM + et * 16 + col] = O[et][r];
            if (col == 0) {
#pragma unroll
                for (int r = 0; r < 4; ++r)
                    pl[(size_t)split * NROW + i0 + quad * 4 + r] = l[r];
            }
        }
    } else {
        // ======== intra-sample attention (one group per block) ========
        const int g = ab - 100 * S;
        const size_t base = (size_t)g * SLEN * DIM;

        ushort_t* Vt = smem;                              // [e][t]  9216 B
        ushort_t* Pb = smem + 64 * LSTR + wave * 16 * LSTR;

        {
            const int r = tid >> 2, seg = tid & 3;
            if (r < SLEN) {
                const uint4* vsrc = (const uint4*)(vib + base + (size_t)r * DIM + seg * 16);
                uint4 vv[2] = {vsrc[0], vsrc[1]};
                ushort_t vtmp[16];
                __builtin_memcpy(vtmp, vv, 32);
#pragma unroll
                for (int i = 0; i < 16; ++i)
                    Vt[(seg * 16 + i) * LSTR + r] = vtmp[i];
            } else {
#pragma unroll
                for (int i = 0; i < 16; ++i)
                    Vt[(seg * 16 + i) * LSTR + r] = 0;
            }
        }
        __syncthreads();

        short8 aK0, aK1;
        {
            const ushort_t* kr = kib + base + (size_t)(wave * 16 + col) * DIM + quad * 8;
            aK0 = *(const short8*)kr;
            aK1 = *(const short8*)(kr + 32);
        }

        floatx4 Sv[4];
#pragma unroll
        for (int jt = 0; jt < 4; ++jt) {
            const ushort_t* qr = qib + base + (size_t)(jt * 16 + col) * DIM + quad * 8;
            const short8 q0 = *(const short8*)qr;
            const short8 q1 = *(const short8*)(qr + 32);
            floatx4 c = (floatx4){0.f, 0.f, 0.f, 0.f};
            c = __builtin_amdgcn_mfma_f32_16x16x32_bf16(aK0, q0, c, 0, 0, 0);
            c = __builtin_amdgcn_mfma_f32_16x16x32_bf16(aK1, q1, c, 0, 0, 0);
            Sv[jt] = c;
        }

#pragma unroll
        for (int jt = 0; jt < 4; ++jt) {
            const int t = jt * 16 + col;
#pragma unroll
            for (int r = 0; r < 4; ++r) {
                float p = fast_exp2(Sv[jt][r] - SM_SHIFT2);
                if (t >= SLEN) p = 0.f;
                Pb[(quad * 4 + r) * LSTR + jt * 16 + col] = f2bu(p);
            }
        }

        const short8 aP0 = *(const short8*)&Pb[col * LSTR + quad * 8];
        const short8 aP1 = *(const short8*)&Pb[col * LSTR + quad * 8 + 32];

        floatx4 rsv = (floatx4){0.f, 0.f, 0.f, 0.f};
        rsv = __builtin_amdgcn_mfma_f32_16x16x32_bf16(aP0, ones, rsv, 0, 0, 0);
        rsv = __builtin_amdgcn_mfma_f32_16x16x32_bf16(aP1, ones, rsv, 0, 0, 0);

#pragma unroll
        for (int et = 0; et < 4; ++et) {
            const short8 v0 = *(const short8*)&Vt[(et * 16 + col) * LSTR + quad * 8];
            const short8 v1 = *(const short8*)&Vt[(et * 16 + col) * LSTR + quad * 8 + 32];
            floatx4 o = (floatx4){0.f, 0.f, 0.f, 0.f};
            o = __builtin_amdgcn_mfma_f32_16x16x32_bf16(aP0, v0, o, 0, 0, 0);
            o = __builtin_amdgcn_mfma_f32_16x16x32_bf16(aP1, v1, o, 0, 0, 0);
#pragma unroll
            for (int r = 0; r < 4; ++r) {
                const int s = wave * 16 + quad * 4 + r;
                if (s < SLEN)
                    outZ[base + (size_t)s * DIM + et * 16 + col] = o[r] / rsv[r];
            }
        }
    }
}

// ---------------- combine split-K partials: plain sums ----------------
__global__ __launch_bounds__(256)
void cs_combine_kernel(const float* __restrict__ pl, const float* __restrict__ pacc,
                       float* __restrict__ outX, int S)
{
    const int row = blockIdx.x * 4 + (threadIdx.x >> 6);
    const int lane = threadIdx.x & 63;
    float l = 0.f, a = 0.f;
    for (int p = 0; p < S; ++p) {
        l += pl[(size_t)p * NROW + row];
        a += pacc[((size_t)p * NROW + row) * DIM + lane];
    }
    outX[(size_t)row * DIM + lane] = a / l;
}

extern "C" void kernel_launch(void* const* d_in, const int* in_sizes, int n_in,
                              void* d_out, int out_size, void* d_ws, size_t ws_size,
                              hipStream_t stream)
{
    (void)in_sizes; (void)n_in; (void)out_size;

    const float* x     = (const float*)d_in[0];
    const float* cb    = (const float*)d_in[1];
    const float* Wq_is = (const float*)d_in[2];  const float* bq_is = (const float*)d_in[3];
    const float* Wk_is = (const float*)d_in[4];  const float* bk_is = (const float*)d_in[5];
    const float* Wv_is = (const float*)d_in[6];  const float* bv_is = (const float*)d_in[7];
    const float* Wq_cs = (const float*)d_in[8];  const float* bq_cs = (const float*)d_in[9];
    const float* Wk_cs = (const float*)d_in[10]; const float* bk_cs = (const float*)d_in[11];
    const float* Wv_cs = (const float*)d_in[12]; const float* bv_cs = (const float*)d_in[13];

    float* outQ = (float*)d_out;
    float* outZ = outQ + (size_t)NROW * DIM;
    float* outX = outZ + (size_t)NROW * DIM;

    const size_t RB    = (size_t)NROW * DIM * sizeof(ushort_t);
    const size_t CBT_B = (size_t)NEMB * DIM * sizeof(float);
    const size_t C2_B  = (size_t)NEMB * sizeof(double);
    const size_t BASE  = 6 * RB + CBT_B + C2_B;
    const size_t PER_SPLIT = (size_t)NROW * DIM * sizeof(float)
                           + (size_t)NROW * sizeof(float);
    int S = 1;
    if (ws_size > BASE) {
        const size_t avail = (ws_size - BASE) / PER_SPLIT;
        S = (avail >= SMAX) ? SMAX : (avail < 1 ? 1 : (int)avail);
    }
    const int direct = (S == 1);

    ushort_t* qib = (ushort_t*)d_ws;
    ushort_t* kib = qib + (size_t)NROW * DIM;
    ushort_t* vib = kib + (size_t)NROW * DIM;
    ushort_t* qcb = vib + (size_t)NROW * DIM;
    ushort_t* kcb = qcb + (size_t)NROW * DIM;
    ushort_t* vtb = kcb + (size_t)NROW * DIM;
    float*    cbT = (float*)((char*)d_ws + 6 * RB);
    double*   c2  = (double*)((char*)d_ws + 6 * RB + CBT_B);
    float*    pacc = (float*)((char*)d_ws + BASE);
    float*    pl   = pacc + (size_t)S * NROW * DIM;

    projprep_kernel<<<602, 256, 0, stream>>>(x,
        Wq_is, Wk_is, Wv_is, Wq_cs, Wk_cs, Wv_cs,
        bq_is, bk_is, bv_is, bq_cs, bk_cs, bv_cs,
        cb, cbT, c2,
        qib, kib, vib, qcb, kcb, vtb);

    attn_quant_kernel<<<NQB + 100 * S + NG, 256, 0, stream>>>(qib, kib, vib, outZ,
                                                              qcb, kcb, vtb,
                                                              pl, pacc, outX,
                                                              x, cb, cbT, c2, outQ,
                                                              S, direct);
    if (!direct)
        cs_combine_kernel<<<NROW / 4, 256, 0, stream>>>(pl, pacc, outX, S);
}

// Round 17
// 54.927 us; speedup vs baseline: 1.5240x; 1.0096x over previous
//
#include <hip/hip_runtime.h>
#include <hip/hip_bf16.h>
#include <math.h>

#define DIM 64
#define NROW 6400          // BS * D_NUM * SLEN
#define SLEN 50
#define NG 128             // BS * D_NUM groups
#define NEMB 512
#define SAMPLE 100         // rows per sample (mask block width)
#define NCHUNK 100         // 6400 / 64 j-chunks
#define NQB 400            // quant blocks FIRST in attn grid (r3-measured: overlap with attn)
#define SMAX 6             // r3/r8 A/B: S=6 beats S=7
#define LOG2E 1.4426950408889634f
#define SM_SHIFT2 11.541560327111707f   // 8 * log2(e): exp(s-8) == exp2(s*log2e - SM_SHIFT2)
#define LSTR 72            // LDS row stride (ushorts): 36 dwords -> 2-way-max b128 reads

typedef unsigned short ushort_t;
typedef __attribute__((ext_vector_type(8))) short short8;
typedef __attribute__((ext_vector_type(4))) float floatx4;

__device__ __forceinline__ ushort_t f2bu(float f) {
    __hip_bfloat16 h = __float2bfloat16(f);
    ushort_t u;
    __builtin_memcpy(&u, &h, 2);
    return u;
}

__device__ __forceinline__ float fast_exp2(float x) {
#if __has_builtin(__builtin_amdgcn_exp2f)
    return __builtin_amdgcn_exp2f(x);
#else
    return exp2f(x);
#endif
}

// ---------------- proj + prep fused, one projection per block (r13 form) ----------------
// blocks 0..599  : proj — block b does projection p = b%6 for row-tile b/6
// blocks 600..601: codebook f32 transpose + f64 norms
__global__ __launch_bounds__(256)
void projprep_kernel(const float* __restrict__ x,
                     const float* __restrict__ W0, const float* __restrict__ W1,
                     const float* __restrict__ W2, const float* __restrict__ W3,
                     const float* __restrict__ W4, const float* __restrict__ W5,
                     const float* __restrict__ b0, const float* __restrict__ b1,
                     const float* __restrict__ b2, const float* __restrict__ b3,
                     const float* __restrict__ b4, const float* __restrict__ b5,
                     const float* __restrict__ cb, float* __restrict__ cbT,
                     double* __restrict__ c2,
                     ushort_t* __restrict__ qib, ushort_t* __restrict__ kib,
                     ushort_t* __restrict__ vib,
                     ushort_t* __restrict__ qcb, ushort_t* __restrict__ kcb,
                     ushort_t* __restrict__ vtb)
{
    const int tid = threadIdx.x;

    if (blockIdx.x >= 600) {
        const int c = (blockIdx.x - 600) * 256 + tid;
        const float* cr = cb + (size_t)c * DIM;
        double s = 0.0;
#pragma unroll 8
        for (int e = 0; e < DIM; ++e) {
            const float v = cr[e];
            cbT[(size_t)e * NEMB + c] = v;
            s = fma((double)v, (double)v, s);
        }
        c2[c] = s;
        return;
    }

    __shared__ __align__(16) ushort_t Xb[64 * LSTR];
    __shared__ __align__(16) ushort_t WL[64 * LSTR];

    const int wave = tid >> 6, lane = tid & 63;
    const int col = lane & 15;
    const int quad = lane >> 4;

    const int r0 = (blockIdx.x / 6) * 64;
    const int p  = blockIdx.x % 6;
    const float scale = (p == 1 || p == 4) ? LOG2E : 1.0f;

    const float* W = (p == 0) ? W0 : (p == 1) ? W1 : (p == 2) ? W2
                   : (p == 3) ? W3 : (p == 4) ? W4 : W5;
    const float* B = (p == 0) ? b0 : (p == 1) ? b1 : (p == 2) ? b2
                   : (p == 3) ? b3 : (p == 4) ? b4 : b5;

    const int kr = tid >> 2, seg = tid & 3;

    {   // stage X tile as bf16
        const float* src = x + (size_t)(r0 + kr) * DIM + seg * 16;
        ushort_t* dst = &Xb[kr * LSTR + seg * 16];
#pragma unroll
        for (int i = 0; i < 16; ++i) dst[i] = f2bu(src[i]);
    }
    {   // transpose W -> WL[n][k], bf16, k-scaled
        const float* wrow = W + (size_t)kr * DIM + seg * 16;
        float wv[16];
#pragma unroll
        for (int i = 0; i < 16; ++i) wv[i] = wrow[i];
#pragma unroll
        for (int i = 0; i < 16; ++i)
            WL[(seg * 16 + i) * LSTR + kr] = f2bu(wv[i] * scale);
    }
    __syncthreads();

    const short8 aX0 = *(const short8*)&Xb[(wave * 16 + col) * LSTR + quad * 8];
    const short8 aX1 = *(const short8*)&Xb[(wave * 16 + col) * LSTR + quad * 8 + 32];

#pragma unroll
    for (int nt = 0; nt < 4; ++nt) {
        const int n = nt * 16 + col;
        float bv = B[n];
        if (p == 1 || p == 4) bv *= LOG2E;
        floatx4 c = (floatx4){bv, bv, bv, bv};
        const ushort_t* wr = &WL[n * LSTR + quad * 8];
        const short8 w0 = *(const short8*)wr;
        const short8 w1 = *(const short8*)(wr + 32);
        c = __builtin_amdgcn_mfma_f32_16x16x32_bf16(aX0, w0, c, 0, 0, 0);
        c = __builtin_amdgcn_mfma_f32_16x16x32_bf16(aX1, w1, c, 0, 0, 0);
#pragma unroll
        for (int r = 0; r < 4; ++r) {
            const int row = r0 + wave * 16 + quad * 4 + r;
            const ushort_t ub = f2bu(c[r]);
            if (p == 0)      qib[(size_t)row * DIM + n] = ub;
            else if (p == 1) kib[(size_t)row * DIM + n] = ub;
            else if (p == 2) vib[(size_t)row * DIM + n] = ub;
            else if (p == 3) qcb[(size_t)row * DIM + n] = ub;
            else if (p == 4) kcb[(size_t)row * DIM + n] = ub;
            else             vtb[(size_t)n * NROW + row] = ub;
        }
    }
}

// ---------------- fused quant + attention ----------------
// blocks [0, NQB)          : f64 quant (round-3 form, byte-identical)
// blocks [NQB, NQB+100*S)  : cross-sample flash attention; SWAPPED QK^T (mfma(Q,K))
//                            makes each lane's P-values j-contiguous -> P written as
//                            4x ds_write_b64 (was 16x b16) and scalar mask window.
//                            Pb contents/layout bit-identical; PV/rsv consumption unchanged.
// blocks [.., +NG)         : intra-sample attention (r13 byte-identical)
// LDS: 27648 B -> 5 blocks/CU; launch_bounds(256,5).
__global__ __launch_bounds__(256, 5)
void attn_quant_kernel(const ushort_t* __restrict__ qib, const ushort_t* __restrict__ kib,
                       const ushort_t* __restrict__ vib, float* __restrict__ outZ,
                       const ushort_t* __restrict__ qcb, const ushort_t* __restrict__ kcb,
                       const ushort_t* __restrict__ vtb,
                       float* __restrict__ pl, float* __restrict__ pacc,
                       float* __restrict__ outX,
                       const float* __restrict__ x, const float* __restrict__ cb,
                       const float* __restrict__ cbT, const double* __restrict__ c2,
                       float* __restrict__ outq,
                       int S, int direct)
{
    __shared__ __align__(16) ushort_t smem[3 * 64 * LSTR];   // 27648 B

    const int tid = threadIdx.x;
    const int wave = tid >> 6;
    const int lane = tid & 63;

    if ((int)blockIdx.x < NQB) {
        // ======== quant: 16 rows x 512 codes, f64 (round-3 chain, bit-identical) ========
        const int r0 = blockIdx.x * 16;

        double* xs    = (double*)smem;           // [16][64]  8192 B
        double* candd = xs + 16 * 64;            // [4][16]    512 B
        int*    candi = (int*)(candd + 64);      // [4][16]    256 B
        int*    sidx  = candi + 64;              // [16]        64 B

        for (int idx = tid; idx < 16 * DIM; idx += 256) {
            const int r = idx >> 6, e = idx & 63;
            xs[r * 64 + e] = (double)x[(size_t)(r0 + r) * DIM + e];
        }
        __syncthreads();

        const int c0 = wave * 64 + lane;
        double dot0[16], dot1[16];
#pragma unroll
        for (int r = 0; r < 16; ++r) { dot0[r] = 0.0; dot1[r] = 0.0; }

        for (int e = 0; e < DIM; ++e) {
            const double ce0 = (double)cbT[(size_t)e * NEMB + c0];
            const double ce1 = (double)cbT[(size_t)e * NEMB + c0 + 256];
#pragma unroll
            for (int r = 0; r < 16; ++r) {
                const double xe = xs[r * 64 + e];
                dot0[r] = fma(xe, ce0, dot0[r]);
                dot1[r] = fma(xe, ce1, dot1[r]);
            }
        }

        const double cc0 = c2[c0];
        const double cc1 = c2[c0 + 256];
#pragma unroll
        for (int r = 0; r < 16; ++r) {
            double bd = cc0 - 2.0 * dot0[r];
            int bi = c0;
            const double d1 = cc1 - 2.0 * dot1[r];
            if (d1 < bd) { bd = d1; bi = c0 + 256; }
            for (int off = 32; off; off >>= 1) {
                const double od = __shfl_down(bd, off, 64);
                const int oi = __shfl_down(bi, off, 64);
                if (od < bd || (od == bd && oi < bi)) { bd = od; bi = oi; }
            }
            if (lane == 0) { candd[wave * 16 + r] = bd; candi[wave * 16 + r] = bi; }
        }
        __syncthreads();
        if (tid < 16) {
            double bd = candd[tid];
            int bi = candi[tid];
#pragma unroll
            for (int w = 1; w < 4; ++w) {
                const double od = candd[w * 16 + tid];
                const int oi = candi[w * 16 + tid];
                if (od < bd || (od == bd && oi < bi)) { bd = od; bi = oi; }
            }
            sidx[tid] = bi;
        }
        __syncthreads();
        for (int idx = tid; idx < 16 * DIM; idx += 256) {
            const int r = idx >> 6, e = idx & 63;
            outq[(size_t)(r0 + r) * DIM + e] = cb[(size_t)sidx[r] * DIM + e];
        }
        return;
    }

    const int ab = blockIdx.x - NQB;
    const int col = lane & 15;
    const int quad = lane >> 4;

    short8 ones;
#pragma unroll
    for (int i = 0; i < 8; ++i) ones[i] = (short)0x3F80;   // bf16 1.0

    if (ab < 100 * S) {
        // ======== cross-sample flash attention: single-buffer staged, swapped QK^T ========
        const int bi = ab / S;
        const int split = ab % S;
        const int i0 = bi * 64 + wave * 16;

        ushort_t* Qs = smem;                       // [64*LSTR]
        ushort_t* Vs = smem + 64 * LSTR;           // [64*LSTR]
        ushort_t* Pb = smem + 2 * 64 * LSTR + wave * 16 * LSTR;

        const int srow = tid >> 2;
        const int sseg = tid & 3;

        short8 aK0, aK1;
        {
            const ushort_t* kr = kcb + (size_t)(i0 + col) * DIM + quad * 8;
            aK0 = *(const short8*)kr;
            aK1 = *(const short8*)(kr + 32);
        }

        // swapped QK^T: this lane produces P[i = i0+col][...]; mask window is scalar
        const int lo_s = ((i0 + col) / SAMPLE) * SAMPLE;

        float l[4];
        floatx4 O[4];
#pragma unroll
        for (int r = 0; r < 4; ++r) l[r] = 0.f;
#pragma unroll
        for (int et = 0; et < 4; ++et) O[et] = (floatx4){0.f, 0.f, 0.f, 0.f};

        {   // prologue: stage first chunk (coalesced)
            const int j0 = split * 64;
            const uint4* qsrc = (const uint4*)(qcb + (size_t)(j0 + srow) * DIM + sseg * 16);
            const uint4* vsrc = (const uint4*)(vtb + (size_t)srow * NROW + j0 + sseg * 16);
            const uint4 q0 = qsrc[0], q1 = qsrc[1];
            const uint4 v0 = vsrc[0], v1 = vsrc[1];
            uint4* qdst = (uint4*)&Qs[srow * LSTR + sseg * 16];
            uint4* vdst = (uint4*)&Vs[srow * LSTR + sseg * 16];
            qdst[0] = q0; qdst[1] = q1;
            vdst[0] = v0; vdst[1] = v1;
        }
        __syncthreads();

        for (int ch = split; ch < NCHUNK; ch += S) {
            const int nxt = ch + S;
            uint4 q0, q1, v0, v1;
            if (nxt < NCHUNK) {   // prefetch next chunk into regs
                const int j0n = nxt * 64;
                const uint4* qsrc = (const uint4*)(qcb + (size_t)(j0n + srow) * DIM + sseg * 16);
                const uint4* vsrc = (const uint4*)(vtb + (size_t)srow * NROW + j0n + sseg * 16);
                q0 = qsrc[0]; q1 = qsrc[1];
                v0 = vsrc[0]; v1 = vsrc[1];
            }

            const int j0 = ch * 64;

            // QK^T, swapped operands: Sv[jt][r] = S[i=i0+col][j = j0 + jt*16 + quad*4 + r]
            floatx4 Sv[4];
#pragma unroll
            for (int jt = 0; jt < 4; ++jt) {
                const short8 b0 = *(const short8*)&Qs[(jt * 16 + col) * LSTR + quad * 8];
                const short8 b1 = *(const short8*)&Qs[(jt * 16 + col) * LSTR + quad * 8 + 32];
                floatx4 c = (floatx4){0.f, 0.f, 0.f, 0.f};
                c = __builtin_amdgcn_mfma_f32_16x16x32_bf16(b0, aK0, c, 0, 0, 0);
                c = __builtin_amdgcn_mfma_f32_16x16x32_bf16(b1, aK1, c, 0, 0, 0);
                Sv[jt] = c;
            }

            // P-phase: 4 j-contiguous values per jt -> one b64 store each
#pragma unroll
            for (int jt = 0; jt < 4; ++jt) {
                const int jbase = j0 + jt * 16 + quad * 4;
                ushort_t pb[4];
#pragma unroll
                for (int r = 0; r < 4; ++r) {
                    float p = fast_exp2(Sv[jt][r] - SM_SHIFT2);
                    if ((unsigned)(jbase + r - lo_s) < SAMPLE) p = 0.f;   // own-sample mask
                    pb[r] = f2bu(p);
                }
                uint2 w;
                __builtin_memcpy(&w, pb, 8);
                *(uint2*)&Pb[col * LSTR + jt * 16 + quad * 4] = w;
            }

            const short8 aP0 = *(const short8*)&Pb[col * LSTR + quad * 8];
            const short8 aP1 = *(const short8*)&Pb[col * LSTR + quad * 8 + 32];

            floatx4 rsv = (floatx4){0.f, 0.f, 0.f, 0.f};
            rsv = __builtin_amdgcn_mfma_f32_16x16x32_bf16(aP0, ones, rsv, 0, 0, 0);
            rsv = __builtin_amdgcn_mfma_f32_16x16x32_bf16(aP1, ones, rsv, 0, 0, 0);
#pragma unroll
            for (int r = 0; r < 4; ++r) l[r] += rsv[r];

#pragma unroll
            for (int et = 0; et < 4; ++et) {
                const short8 b0 = *(const short8*)&Vs[(et * 16 + col) * LSTR + quad * 8];
                const short8 b1 = *(const short8*)&Vs[(et * 16 + col) * LSTR + quad * 8 + 32];
                O[et] = __builtin_amdgcn_mfma_f32_16x16x32_bf16(aP0, b0, O[et], 0, 0, 0);
                O[et] = __builtin_amdgcn_mfma_f32_16x16x32_bf16(aP1, b1, O[et], 0, 0, 0);
            }

            if (nxt < NCHUNK) {
                __syncthreads();   // all waves done reading Qs/Vs
                uint4* qdst = (uint4*)&Qs[srow * LSTR + sseg * 16];
                uint4* vdst = (uint4*)&Vs[srow * LSTR + sseg * 16];
                qdst[0] = q0; qdst[1] = q1;
                vdst[0] = v0; vdst[1] = v1;
                __syncthreads();   // writes visible
            }
        }

        if (direct) {
#pragma unroll
            for (int et = 0; et < 4; ++et)
#pragma unroll
                for (int r = 0; r < 4; ++r)
                    outX[(size_t)(i0 + quad * 4 + r) * DIM + et * 16 + col] = O[et][r] / l[r];
        } else {
#pragma unroll
            for (int et = 0; et < 4; ++et)
#pragma unroll
                for (int r = 0; r < 4; ++r)
                    pacc[((size_t)split * NROW + i0 + quad * 4 + r) * DIM + et * 16 + col] = O[et][r];
            if (col == 0) {
#pragma unroll
                for (int r = 0; r < 4; ++r)
                    pl[(size_t)split * NROW + i0 + quad * 4 + r] = l[r];
            }
        }
    } else {
        // ======== intra-sample attention (one group per block) ========
        const int g = ab - 100 * S;
        const size_t base = (size_t)g * SLEN * DIM;

        ushort_t* Vt = smem;                              // [e][t]  9216 B
        ushort_t* Pb = smem + 64 * LSTR + wave * 16 * LSTR;

        {
            const int r = tid >> 2, seg = tid & 3;
            if (r < SLEN) {
                const uint4* vsrc = (const uint4*)(vib + base + (size_t)r * DIM + seg * 16);
                uint4 vv[2] = {vsrc[0], vsrc[1]};
                ushort_t vtmp[16];
                __builtin_memcpy(vtmp, vv, 32);
#pragma unroll
                for (int i = 0; i < 16; ++i)
                    Vt[(seg * 16 + i) * LSTR + r] = vtmp[i];
            } else {
#pragma unroll
                for (int i = 0; i < 16; ++i)
                    Vt[(seg * 16 + i) * LSTR + r] = 0;
            }
        }
        __syncthreads();

        short8 aK0, aK1;
        {
            const ushort_t* kr = kib + base + (size_t)(wave * 16 + col) * DIM + quad * 8;
            aK0 = *(const short8*)kr;
            aK1 = *(const short8*)(kr + 32);
        }

        floatx4 Sv[4];
#pragma unroll
        for (int jt = 0; jt < 4; ++jt) {
            const ushort_t* qr = qib + base + (size_t)(jt * 16 + col) * DIM + quad * 8;
            const short8 q0 = *(const short8*)qr;
            const short8 q1 = *(const short8*)(qr + 32);
            floatx4 c = (floatx4){0.f, 0.f, 0.f, 0.f};
            c = __builtin_amdgcn_mfma_f32_16x16x32_bf16(aK0, q0, c, 0, 0, 0);
            c = __builtin_amdgcn_mfma_f32_16x16x32_bf16(aK1, q1, c, 0, 0, 0);
            Sv[jt] = c;
        }

#pragma unroll
        for (int jt = 0; jt < 4; ++jt) {
            const int t = jt * 16 + col;
#pragma unroll
            for (int r = 0; r < 4; ++r) {
                float p = fast_exp2(Sv[jt][r] - SM_SHIFT2);
                if (t >= SLEN) p = 0.f;
                Pb[(quad * 4 + r) * LSTR + jt * 16 + col] = f2bu(p);
            }
        }

        const short8 aP0 = *(const short8*)&Pb[col * LSTR + quad * 8];
        const short8 aP1 = *(const short8*)&Pb[col * LSTR + quad * 8 + 32];

        floatx4 rsv = (floatx4){0.f, 0.f, 0.f, 0.f};
        rsv = __builtin_amdgcn_mfma_f32_16x16x32_bf16(aP0, ones, rsv, 0, 0, 0);
        rsv = __builtin_amdgcn_mfma_f32_16x16x32_bf16(aP1, ones, rsv, 0, 0, 0);

#pragma unroll
        for (int et = 0; et < 4; ++et) {
            const short8 v0 = *(const short8*)&Vt[(et * 16 + col) * LSTR + quad * 8];
            const short8 v1 = *(const short8*)&Vt[(et * 16 + col) * LSTR + quad * 8 + 32];
            floatx4 o = (floatx4){0.f, 0.f, 0.f, 0.f};
            o = __builtin_amdgcn_mfma_f32_16x16x32_bf16(aP0, v0, o, 0, 0, 0);
            o = __builtin_amdgcn_mfma_f32_16x16x32_bf16(aP1, v1, o, 0, 0, 0);
#pragma unroll
            for (int r = 0; r < 4; ++r) {
                const int s = wave * 16 + quad * 4 + r;
                if (s < SLEN)
                    outZ[base + (size_t)s * DIM + et * 16 + col] = o[r] / rsv[r];
            }
        }
    }
}

// ---------------- combine split-K partials: plain sums ----------------
__global__ __launch_bounds__(256)
void cs_combine_kernel(const float* __restrict__ pl, const float* __restrict__ pacc,
                       float* __restrict__ outX, int S)
{
    const int row = blockIdx.x * 4 + (threadIdx.x >> 6);
    const int lane = threadIdx.x & 63;
    float l = 0.f, a = 0.f;
    for (int p = 0; p < S; ++p) {
        l += pl[(size_t)p * NROW + row];
        a += pacc[((size_t)p * NROW + row) * DIM + lane];
    }
    outX[(size_t)row * DIM + lane] = a / l;
}

extern "C" void kernel_launch(void* const* d_in, const int* in_sizes, int n_in,
                              void* d_out, int out_size, void* d_ws, size_t ws_size,
                              hipStream_t stream)
{
    (void)in_sizes; (void)n_in; (void)out_size;

    const float* x     = (const float*)d_in[0];
    const float* cb    = (const float*)d_in[1];
    const float* Wq_is = (const float*)d_in[2];  const float* bq_is = (const float*)d_in[3];
    const float* Wk_is = (const float*)d_in[4];  const float* bk_is = (const float*)d_in[5];
    const float* Wv_is = (const float*)d_in[6];  const float* bv_is = (const float*)d_in[7];
    const float* Wq_cs = (const float*)d_in[8];  const float* bq_cs = (const float*)d_in[9];
    const float* Wk_cs = (const float*)d_in[10]; const float* bk_cs = (const float*)d_in[11];
    const float* Wv_cs = (const float*)d_in[12]; const float* bv_cs = (const float*)d_in[13];

    float* outQ = (float*)d_out;
    float* outZ = outQ + (size_t)NROW * DIM;
    float* outX = outZ + (size_t)NROW * DIM;

    const size_t RB    = (size_t)NROW * DIM * sizeof(ushort_t);
    const size_t CBT_B = (size_t)NEMB * DIM * sizeof(float);
    const size_t C2_B  = (size_t)NEMB * sizeof(double);
    const size_t BASE  = 6 * RB + CBT_B + C2_B;
    const size_t PER_SPLIT = (size_t)NROW * DIM * sizeof(float)
                           + (size_t)NROW * sizeof(float);
    int S = 1;
    if (ws_size > BASE) {
        const size_t avail = (ws_size - BASE) / PER_SPLIT;
        S = (avail >= SMAX) ? SMAX : (avail < 1 ? 1 : (int)avail);
    }
    const int direct = (S == 1);

    ushort_t* qib = (ushort_t*)d_ws;
    ushort_t* kib = qib + (size_t)NROW * DIM;
    ushort_t* vib = kib + (size_t)NROW * DIM;
    ushort_t* qcb = vib + (size_t)NROW * DIM;
    ushort_t* kcb = qcb + (size_t)NROW * DIM;
    ushort_t* vtb = kcb + (size_t)NROW * DIM;
    float*    cbT = (float*)((char*)d_ws + 6 * RB);
    double*   c2  = (double*)((char*)d_ws + 6 * RB + CBT_B);
    float*    pacc = (float*)((char*)d_ws + BASE);
    float*    pl   = pacc + (size_t)S * NROW * DIM;

    projprep_kernel<<<602, 256, 0, stream>>>(x,
        Wq_is, Wk_is, Wv_is, Wq_cs, Wk_cs, Wv_cs,
        bq_is, bk_is, bv_is, bq_cs, bk_cs, bv_cs,
        cb, cbT, c2,
        qib, kib, vib, qcb, kcb, vtb);

    attn_quant_kernel<<<NQB + 100 * S + NG, 256, 0, stream>>>(qib, kib, vib, outZ,
                                                              qcb, kcb, vtb,
                                                              pl, pacc, outX,
                                                              x, cb, cbT, c2, outQ,
                                                              S, direct);
    if (!direct)
        cs_combine_kernel<<<NROW / 4, 256, 0, stream>>>(pl, pacc, outX, S);
}